// Round 2
// baseline (353.344 us; speedup 1.0000x reference)
//
#include <hip/hip_runtime.h>

typedef unsigned short u16;
typedef unsigned int u32;
typedef __attribute__((ext_vector_type(8))) short short8;
typedef __attribute__((ext_vector_type(4))) float f32x4;

#define NDST 32000
#define NSRC 50000
#define MAXDEG 16
#define DH 128
#define TSTEPS 15
#define NCLS 104

#define MFMA(a, b, c) __builtin_amdgcn_mfma_f32_16x16x32_bf16(a, b, c, 0, 0, 0)

__device__ __forceinline__ u16 f2bf(float f) {
  union { float f; u32 u; } v; v.f = f;
  return (u16)((v.u + 0x7FFFu + ((v.u >> 16) & 1u)) >> 16);
}
__device__ __forceinline__ float sigm(float x) { return 1.f / (1.f + __expf(-x)); }
__device__ __forceinline__ float tanhfast(float x) {
  float ax = fabsf(x);
  float e = __expf(2.f * ax);
  float t = 1.f - 2.f / (e + 1.f);
  return copysignf(t, x);
}
__device__ __forceinline__ f32x4 splat4(float x) { f32x4 v = {x, x, x, x}; return v; }

// Convert weights to bf16; pad classifier weight to 112 rows (7 N-tiles of 16).
__global__ void k_prep(const float* __restrict__ wih, const float* __restrict__ whh,
                       const float* __restrict__ wc,
                       u16* __restrict__ wihb, u16* __restrict__ whhb, u16* __restrict__ wcb) {
  int i = blockIdx.x * 256 + threadIdx.x;
  if (i < 384 * DH) { wihb[i] = f2bf(wih[i]); whhb[i] = f2bf(whh[i]); }
  if (i < 112 * DH) { int r = i >> 7; wcb[i] = (r < NCLS) ? f2bf(wc[i]) : (u16)0; }
}

// feat_src = mean over 4 subtoken embeddings, stored bf16 row-major [NSRC][128].
__global__ void k_embed(const int* __restrict__ token, const float* __restrict__ emb,
                        u16* __restrict__ featb) {
  int gid = blockIdx.x * 256 + threadIdx.x;
  if (gid >= NSRC * 16) return;
  int n = gid >> 4, c = gid & 15;  // 16 threads/node, 8 floats each
  const int* tk = token + n * 4;
  float a[8];
#pragma unroll
  for (int j = 0; j < 8; ++j) a[j] = 0.f;
#pragma unroll
  for (int s = 0; s < 4; ++s) {
    const float* p = emb + (size_t)tk[s] * DH + c * 8;
#pragma unroll
    for (int j = 0; j < 8; ++j) a[j] += p[j];
  }
  u16 u[8];
#pragma unroll
  for (int j = 0; j < 8; ++j) u[j] = f2bf(a[j] * 0.25f);
  uint4 pk;
  pk.x = u[0] | ((u32)u[1] << 16);
  pk.y = u[2] | ((u32)u[3] << 16);
  pk.z = u[4] | ((u32)u[5] << 16);
  pk.w = u[6] | ((u32)u[7] << 16);
  *reinterpret_cast<uint4*>(featb + (size_t)n * DH + c * 8) = pk;
}

// Fused GRU (15 steps) + LayerNorm + deg==1 override + classifier.
// Block = 256 threads (4 waves), 32 dst nodes per block (2 M-tiles of 16).
// Wave w owns feature columns [32w, 32w+32) of each gate (2 col-tiles of 16).
__global__ __launch_bounds__(256) void k_gru(
    const int* __restrict__ neigh, const int* __restrict__ deg,
    const u16* __restrict__ featb,
    const u16* __restrict__ wihb, const u16* __restrict__ whhb,
    const float* __restrict__ bih, const float* __restrict__ bhh,
    const float* __restrict__ gamma, const float* __restrict__ beta,
    const u16* __restrict__ wcb, const float* __restrict__ bc,
    float* __restrict__ out) {
  __shared__ u16 Hb[2][32][DH];        // h in bf16, XOR-swizzled, double-buffered
  __shared__ int neigh_s[MAXDEG][32];  // transposed: [t][node]
  __shared__ int deg_s[32];
  __shared__ float Hf[32][DH + 1];     // final h fp32 for LN
  __shared__ u16 Ft[32][DH];           // classifier input bf16, swizzled

  const int tid = threadIdx.x;
  const int w = tid >> 6;
  const int l = tid & 63;
  const int l16 = l & 15;
  const int lq = l >> 4;
  const int nbase = blockIdx.x * 32;
  const int d0 = w * 32;

  for (int i = tid; i < 32 * MAXDEG; i += 256) {
    int node = i >> 4, t = i & 15;
    neigh_s[t][node] = neigh[(size_t)(nbase + node) * MAXDEG + t];
  }
  if (tid < 32) deg_s[tid] = deg[nbase + tid];
  for (int i = tid; i < 32 * DH; i += 256) ((u16*)Hb[0])[i] = 0;

  // per-lane gate biases (column = d0 + dt*16 + l16)
  float bR[2], bZ[2], bXN[2], bHN[2];
#pragma unroll
  for (int dt = 0; dt < 2; ++dt) {
    int d = d0 + dt * 16 + l16;
    bR[dt] = bih[d] + bhh[d];
    bZ[dt] = bih[DH + d] + bhh[DH + d];
    bXN[dt] = bih[2 * DH + d];
    bHN[dt] = bhh[2 * DH + d];
  }
  float hreg[2][2][4];  // [Mtile][dtile][reg] fp32 master copy of h
#pragma unroll
  for (int m = 0; m < 2; ++m)
#pragma unroll
    for (int dt = 0; dt < 2; ++dt)
#pragma unroll
      for (int r = 0; r < 4; ++r) hreg[m][dt][r] = 0.f;

  __syncthreads();

  int degm1[2][4];  // deg-1 for node = m*16 + lq*4 + r
#pragma unroll
  for (int m = 0; m < 2; ++m)
#pragma unroll
    for (int r = 0; r < 4; ++r) degm1[m][r] = deg_s[m * 16 + lq * 4 + r] - 1;

  int cur = 0;
  for (int t = 0; t < TSTEPS; ++t) {
    f32x4 aR[2][2], aZ[2][2], aXN[2][2], aHN[2][2];
#pragma unroll
    for (int m = 0; m < 2; ++m)
#pragma unroll
      for (int dt = 0; dt < 2; ++dt) {
        aR[m][dt] = splat4(bR[dt]);
        aZ[m][dt] = splat4(bZ[dt]);
        aXN[m][dt] = splat4(bXN[dt]);
        aHN[m][dt] = splat4(bHN[dt]);
      }
    int src0 = neigh_s[t][l16];
    int src1 = neigh_s[t][16 + l16];
#pragma unroll
    for (int kc = 0; kc < 4; ++kc) {
      int koff = kc * 32 + lq * 8;
      // A operands: X gathered from global, H from swizzled LDS
      short8 ax0 = *reinterpret_cast<const short8*>(featb + (size_t)src0 * DH + koff);
      short8 ax1 = *reinterpret_cast<const short8*>(featb + (size_t)src1 * DH + koff);
      int r0 = l16, r1 = 16 + l16;
      short8 ah0 = *reinterpret_cast<const short8*>(&Hb[cur][r0][koff ^ ((r0 & 7) << 3)]);
      short8 ah1 = *reinterpret_cast<const short8*>(&Hb[cur][r1][koff ^ ((r1 & 7) << 3)]);
#pragma unroll
      for (int dt = 0; dt < 2; ++dt) {
        int cb = d0 + dt * 16 + l16;  // weight row (= output feature) this lane supplies
        short8 Br = *reinterpret_cast<const short8*>(wihb + (size_t)cb * DH + koff);
        short8 Bz = *reinterpret_cast<const short8*>(wihb + (size_t)(cb + DH) * DH + koff);
        short8 Bn = *reinterpret_cast<const short8*>(wihb + (size_t)(cb + 2 * DH) * DH + koff);
        short8 Cr = *reinterpret_cast<const short8*>(whhb + (size_t)cb * DH + koff);
        short8 Cz = *reinterpret_cast<const short8*>(whhb + (size_t)(cb + DH) * DH + koff);
        short8 Cn = *reinterpret_cast<const short8*>(whhb + (size_t)(cb + 2 * DH) * DH + koff);
        aR[0][dt] = MFMA(ax0, Br, aR[0][dt]);
        aR[1][dt] = MFMA(ax1, Br, aR[1][dt]);
        aR[0][dt] = MFMA(ah0, Cr, aR[0][dt]);
        aR[1][dt] = MFMA(ah1, Cr, aR[1][dt]);
        aZ[0][dt] = MFMA(ax0, Bz, aZ[0][dt]);
        aZ[1][dt] = MFMA(ax1, Bz, aZ[1][dt]);
        aZ[0][dt] = MFMA(ah0, Cz, aZ[0][dt]);
        aZ[1][dt] = MFMA(ah1, Cz, aZ[1][dt]);
        aXN[0][dt] = MFMA(ax0, Bn, aXN[0][dt]);
        aXN[1][dt] = MFMA(ax1, Bn, aXN[1][dt]);
        aHN[0][dt] = MFMA(ah0, Cn, aHN[0][dt]);
        aHN[1][dt] = MFMA(ah1, Cn, aHN[1][dt]);
      }
    }
    int nxt = cur ^ 1;
#pragma unroll
    for (int m = 0; m < 2; ++m)
#pragma unroll
      for (int dt = 0; dt < 2; ++dt)
#pragma unroll
        for (int r = 0; r < 4; ++r) {
          float rr = sigm(aR[m][dt][r]);
          float zz = sigm(aZ[m][dt][r]);
          float nn = tanhfast(aXN[m][dt][r] + rr * aHN[m][dt][r]);
          float hN = (1.f - zz) * nn + zz * hreg[m][dt][r];
          if (t < degm1[m][r]) hreg[m][dt][r] = hN;
          int row = m * 16 + lq * 4 + r;
          int e = d0 + dt * 16 + l16;
          Hb[nxt][row][e ^ ((row & 7) << 3)] = f2bf(hreg[m][dt][r]);
        }
    __syncthreads();
    cur = nxt;
  }

  // final h -> LDS fp32 for LayerNorm
#pragma unroll
  for (int m = 0; m < 2; ++m)
#pragma unroll
    for (int dt = 0; dt < 2; ++dt)
#pragma unroll
      for (int r = 0; r < 4; ++r) {
        int row = m * 16 + lq * 4 + r;
        Hf[row][d0 + dt * 16 + l16] = hreg[m][dt][r];
      }
  __syncthreads();

  // LayerNorm (8 threads per node) + deg==1 override, write bf16 swizzled Ft
  {
    int node = tid >> 3;
    int sub = tid & 7;
    float v[16];
    float s = 0.f, s2 = 0.f;
#pragma unroll
    for (int j = 0; j < 16; ++j) {
      v[j] = Hf[node][sub * 16 + j];
      s += v[j];
      s2 += v[j] * v[j];
    }
    s += __shfl_xor(s, 1, 64); s2 += __shfl_xor(s2, 1, 64);
    s += __shfl_xor(s, 2, 64); s2 += __shfl_xor(s2, 2, 64);
    s += __shfl_xor(s, 4, 64); s2 += __shfl_xor(s2, 4, 64);
    float mu = s * (1.f / 128.f);
    float var = s2 * (1.f / 128.f) - mu * mu;
    float rstd = rsqrtf(var + 1e-5f);
    bool isd1 = (deg_s[node] == 1);
    const u16* f1 = featb + (size_t)neigh_s[0][node] * DH;
    u16 ob[16];
#pragma unroll
    for (int j = 0; j < 16; ++j) {
      int d = sub * 16 + j;
      float ln = (v[j] - mu) * rstd * gamma[d] + beta[d];
      ob[j] = isd1 ? f1[d] : f2bf(ln);
    }
#pragma unroll
    for (int c = 0; c < 2; ++c) {
      int e = (sub * 16 + c * 8) ^ ((node & 7) << 3);
      uint4 pk;
      pk.x = ob[c * 8 + 0] | ((u32)ob[c * 8 + 1] << 16);
      pk.y = ob[c * 8 + 2] | ((u32)ob[c * 8 + 3] << 16);
      pk.z = ob[c * 8 + 4] | ((u32)ob[c * 8 + 5] << 16);
      pk.w = ob[c * 8 + 6] | ((u32)ob[c * 8 + 7] << 16);
      *reinterpret_cast<uint4*>(&Ft[node][e]) = pk;
    }
  }
  __syncthreads();

  // classifier: out[32,104] = Ft @ wc^T + bc ; wave w handles N-tiles {w, w+4}
  {
    f32x4 aC[2][2];
#pragma unroll
    for (int m = 0; m < 2; ++m)
#pragma unroll
      for (int q = 0; q < 2; ++q) aC[m][q] = splat4(0.f);
    int nt0 = w, nt1 = w + 4;
    bool has1 = (nt1 < 7);
#pragma unroll
    for (int kc = 0; kc < 4; ++kc) {
      int koff = kc * 32 + lq * 8;
      int r0 = l16, r1 = 16 + l16;
      short8 a0 = *reinterpret_cast<const short8*>(&Ft[r0][koff ^ ((r0 & 7) << 3)]);
      short8 a1 = *reinterpret_cast<const short8*>(&Ft[r1][koff ^ ((r1 & 7) << 3)]);
      short8 b0 = *reinterpret_cast<const short8*>(wcb + (size_t)(nt0 * 16 + l16) * DH + koff);
      aC[0][0] = MFMA(a0, b0, aC[0][0]);
      aC[1][0] = MFMA(a1, b0, aC[1][0]);
      if (has1) {
        short8 b1 = *reinterpret_cast<const short8*>(wcb + (size_t)(nt1 * 16 + l16) * DH + koff);
        aC[0][1] = MFMA(a0, b1, aC[0][1]);
        aC[1][1] = MFMA(a1, b1, aC[1][1]);
      }
    }
#pragma unroll
    for (int q = 0; q < 2; ++q) {
      if (q == 1 && !has1) break;
      int nt = (q == 0) ? nt0 : nt1;
      int col = nt * 16 + l16;
      if (col < NCLS) {
        float bcv = bc[col];
#pragma unroll
        for (int m = 0; m < 2; ++m)
#pragma unroll
          for (int r = 0; r < 4; ++r) {
            int rowg = nbase + m * 16 + lq * 4 + r;
            out[(size_t)rowg * NCLS + col] = aC[m][q][r] + bcv;
          }
      }
    }
  }
}

extern "C" void kernel_launch(void* const* d_in, const int* in_sizes, int n_in,
                              void* d_out, int out_size, void* d_ws, size_t ws_size,
                              hipStream_t stream) {
  const int* token = (const int*)d_in[0];
  const int* neigh = (const int*)d_in[1];
  const int* deg = (const int*)d_in[2];
  const float* emb = (const float*)d_in[3];
  const float* wih = (const float*)d_in[4];
  const float* whh = (const float*)d_in[5];
  const float* bih = (const float*)d_in[6];
  const float* bhh = (const float*)d_in[7];
  const float* gamma = (const float*)d_in[8];
  const float* beta = (const float*)d_in[9];
  const float* wc = (const float*)d_in[10];
  const float* bc = (const float*)d_in[11];
  float* out = (float*)d_out;

  u16* featb = (u16*)d_ws;                  // 50000*128 bf16 = 12.8 MB
  u16* wihb = featb + (size_t)NSRC * DH;    // 384*128
  u16* whhb = wihb + 384 * DH;              // 384*128
  u16* wcb = whhb + 384 * DH;               // 112*128 (padded)

  hipLaunchKernelGGL(k_prep, dim3(192), dim3(256), 0, stream, wih, whh, wc, wihb, whhb, wcb);
  hipLaunchKernelGGL(k_embed, dim3((NSRC * 16 + 255) / 256), dim3(256), 0, stream, token, emb, featb);
  hipLaunchKernelGGL(k_gru, dim3(NDST / 32), dim3(256), 0, stream, neigh, deg, featb,
                     wihb, whhb, bih, bhh, gamma, beta, wcb, bc, out);
}

// Round 3
// 268.969 us; speedup vs baseline: 1.3137x; 1.3137x over previous
//
#include <hip/hip_runtime.h>

typedef unsigned short u16;
typedef unsigned int u32;
typedef __attribute__((ext_vector_type(8))) short short8;
typedef __attribute__((ext_vector_type(4))) float f32x4;

#define NDST 32000
#define NSRC 50000
#define MAXDEG 16
#define DH 128
#define TSTEPS 15
#define NCLS 104
#define SBLK 125  // 32000/256 sort blocks

#define MFMA(a, b, c) __builtin_amdgcn_mfma_f32_16x16x32_bf16(a, b, c, 0, 0, 0)

__device__ __forceinline__ u16 f2bf(float f) {
  union { float f; u32 u; } v; v.f = f;
  return (u16)((v.u + 0x7FFFu + ((v.u >> 16) & 1u)) >> 16);
}
__device__ __forceinline__ float sigm(float x) { return 1.f / (1.f + __expf(-x)); }
__device__ __forceinline__ float tanhfast(float x) {
  float ax = fabsf(x);
  float e = __expf(2.f * ax);
  float t = 1.f - 2.f / (e + 1.f);
  return copysignf(t, x);
}
__device__ __forceinline__ f32x4 splat4(float x) { f32x4 v = {x, x, x, x}; return v; }

// Convert weights to bf16; pad classifier weight to 112 rows.
__global__ void k_prep(const float* __restrict__ wih, const float* __restrict__ whh,
                       const float* __restrict__ wc,
                       u16* __restrict__ wihb, u16* __restrict__ whhb, u16* __restrict__ wcb) {
  int i = blockIdx.x * 256 + threadIdx.x;
  if (i < 384 * DH) { wihb[i] = f2bf(wih[i]); whhb[i] = f2bf(whh[i]); }
  if (i < 112 * DH) { int r = i >> 7; wcb[i] = (r < NCLS) ? f2bf(wc[i]) : (u16)0; }
}

// feat_src = mean over 4 subtoken embeddings, bf16 row-major [NSRC][128].
__global__ void k_embed(const int* __restrict__ token, const float* __restrict__ emb,
                        u16* __restrict__ featb) {
  int gid = blockIdx.x * 256 + threadIdx.x;
  if (gid >= NSRC * 16) return;
  int n = gid >> 4, c = gid & 15;
  const int* tk = token + n * 4;
  float a[8];
#pragma unroll
  for (int j = 0; j < 8; ++j) a[j] = 0.f;
#pragma unroll
  for (int s = 0; s < 4; ++s) {
    const float* p = emb + (size_t)tk[s] * DH + c * 8;
#pragma unroll
    for (int j = 0; j < 8; ++j) a[j] += p[j];
  }
  u16 u[8];
#pragma unroll
  for (int j = 0; j < 8; ++j) u[j] = f2bf(a[j] * 0.25f);
  uint4 pk;
  pk.x = u[0] | ((u32)u[1] << 16);
  pk.y = u[2] | ((u32)u[3] << 16);
  pk.z = u[4] | ((u32)u[5] << 16);
  pk.w = u[6] | ((u32)u[7] << 16);
  *reinterpret_cast<uint4*>(featb + (size_t)n * DH + c * 8) = pk;
}

// ---- degree counting sort (no global atomics) ----
__global__ void k_hist(const int* __restrict__ deg, int* __restrict__ blkhist) {
  __shared__ int h[16];
  int tid = threadIdx.x;
  if (tid < 16) h[tid] = 0;
  __syncthreads();
  int node = blockIdx.x * 256 + tid;
  atomicAdd(&h[deg[node] - 1], 1);
  __syncthreads();
  if (tid < 16) blkhist[blockIdx.x * 16 + tid] = h[tid];
}

__global__ void k_scan(const int* __restrict__ blkhist, int* __restrict__ offs,
                       int* __restrict__ base16) {
  __shared__ int tot[16];
  int k = threadIdx.x;
  if (k < 16) {
    int run = 0;
    for (int b = 0; b < SBLK; ++b) { offs[b * 16 + k] = run; run += blkhist[b * 16 + k]; }
    tot[k] = run;
  }
  __syncthreads();
  if (k == 0) {
    int run = 0;
    for (int i = 0; i < 16; ++i) { base16[i] = run; run += tot[i]; }
  }
}

__global__ void k_scatter(const int* __restrict__ deg, const int* __restrict__ offs,
                          const int* __restrict__ base16, int* __restrict__ perm) {
  __shared__ int lc[16];
  int tid = threadIdx.x;
  if (tid < 16) lc[tid] = 0;
  __syncthreads();
  int node = blockIdx.x * 256 + tid;
  int k = deg[node] - 1;
  int p = atomicAdd(&lc[k], 1);
  perm[base16[k] + offs[blockIdx.x * 16 + k] + p] = node;
}

// ---- fused GRU + LN + classifier ----
// 512 threads = 8 waves; 32 (degree-sorted) nodes per block.
// Wave w owns output columns [16w,16w+16) of every gate; weights live in
// registers (96 VGPR/lane); X-gathers are 1-step register-prefetched.
__global__ __launch_bounds__(512, 2) void k_gru(
    const int* __restrict__ neigh, const int* __restrict__ deg,
    const int* __restrict__ perm, const u16* __restrict__ featb,
    const u16* __restrict__ wihb, const u16* __restrict__ whhb,
    const float* __restrict__ bih, const float* __restrict__ bhh,
    const float* __restrict__ gamma, const float* __restrict__ beta,
    const u16* __restrict__ wcb, const float* __restrict__ bc,
    float* __restrict__ out) {
  __shared__ u16 Hb[2][32][DH];  // h bf16, XOR-swizzled, double-buffered
  __shared__ int nid_s[32];
  __shared__ int neigh_s[MAXDEG][32];
  __shared__ int deg_s[32];
  __shared__ int smax;
  __shared__ float Hf[32][DH + 1];
  __shared__ u16 Ft[32][DH];

  const int tid = threadIdx.x;
  const int w = tid >> 6;
  const int l = tid & 63;
  const int l16 = l & 15;
  const int lq = l >> 4;
  const int col = w * 16 + l16;       // output column this lane owns
  const int swzA = (l16 & 7) << 3;    // read-side XOR (rows l16 / 16+l16)

  if (tid < 32) nid_s[tid] = perm[blockIdx.x * 32 + tid];
  if (tid == 0) smax = 1;
  __syncthreads();
  {
    int node = tid >> 4, t = tid & 15;  // 512 threads cover 32x16 exactly
    neigh_s[t][node] = neigh[(size_t)nid_s[node] * MAXDEG + t];
  }
  if (tid < 32) { int d = deg[nid_s[tid]]; deg_s[tid] = d; atomicMax(&smax, d); }
  for (int i = tid; i < 32 * DH / 2; i += 512) ((u32*)Hb[0])[i] = 0;

  // weights resident: 24 x short8 = 96 VGPR
  short8 Wr[4], Wz[4], Wn[4], Ur[4], Uz[4], Un[4];
#pragma unroll
  for (int kc = 0; kc < 4; ++kc) {
    int ko = kc * 32 + lq * 8;
    const u16* pw = wihb + (size_t)col * DH + ko;
    const u16* pu = whhb + (size_t)col * DH + ko;
    Wr[kc] = *(const short8*)pw;
    Wz[kc] = *(const short8*)(pw + DH * DH);
    Wn[kc] = *(const short8*)(pw + 2 * DH * DH);
    Ur[kc] = *(const short8*)pu;
    Uz[kc] = *(const short8*)(pu + DH * DH);
    Un[kc] = *(const short8*)(pu + 2 * DH * DH);
  }
  const float bR = bih[col] + bhh[col];
  const float bZ = bih[DH + col] + bhh[DH + col];
  const float bXN = bih[2 * DH + col];
  const float bHN = bhh[2 * DH + col];
  float hreg[2][4] = {{0, 0, 0, 0}, {0, 0, 0, 0}};
  __syncthreads();

  int degm1[2][4];
#pragma unroll
  for (int m = 0; m < 2; ++m)
#pragma unroll
    for (int r = 0; r < 4; ++r) degm1[m][r] = deg_s[m * 16 + lq * 4 + r] - 1;
  const int tmax = smax - 1;

  // prefetch t=0 X-fragments
  short8 axA[2][4], axB[2][4];
  {
    int s0 = neigh_s[0][l16], s1 = neigh_s[0][16 + l16];
#pragma unroll
    for (int kc = 0; kc < 4; ++kc) {
      int ko = kc * 32 + lq * 8;
      axA[0][kc] = *(const short8*)(featb + (size_t)s0 * DH + ko);
      axA[1][kc] = *(const short8*)(featb + (size_t)s1 * DH + ko);
    }
  }

#define GRU_STEP(T, AXC, AXN, BR, BW)                                          \
  do {                                                                         \
    int sn0 = neigh_s[(T) + 1][l16], sn1 = neigh_s[(T) + 1][16 + l16];         \
    _Pragma("unroll") for (int kc = 0; kc < 4; ++kc) {                         \
      int ko = kc * 32 + lq * 8;                                               \
      AXN[0][kc] = *(const short8*)(featb + (size_t)sn0 * DH + ko);            \
      AXN[1][kc] = *(const short8*)(featb + (size_t)sn1 * DH + ko);            \
    }                                                                          \
    f32x4 aR0 = splat4(bR), aR1 = splat4(bR), aZ0 = splat4(bZ),                \
          aZ1 = splat4(bZ), aN0 = splat4(bXN), aN1 = splat4(bXN),              \
          aH0 = splat4(bHN), aH1 = splat4(bHN);                                \
    _Pragma("unroll") for (int kc = 0; kc < 4; ++kc) {                         \
      int ko = kc * 32 + lq * 8;                                               \
      short8 ah0 = *(const short8*)&BR[l16][ko ^ swzA];                        \
      short8 ah1 = *(const short8*)&BR[16 + l16][ko ^ swzA];                   \
      aR0 = MFMA(AXC[0][kc], Wr[kc], aR0);                                     \
      aR1 = MFMA(AXC[1][kc], Wr[kc], aR1);                                     \
      aZ0 = MFMA(AXC[0][kc], Wz[kc], aZ0);                                     \
      aZ1 = MFMA(AXC[1][kc], Wz[kc], aZ1);                                     \
      aN0 = MFMA(AXC[0][kc], Wn[kc], aN0);                                     \
      aN1 = MFMA(AXC[1][kc], Wn[kc], aN1);                                     \
      aR0 = MFMA(ah0, Ur[kc], aR0);                                            \
      aR1 = MFMA(ah1, Ur[kc], aR1);                                            \
      aZ0 = MFMA(ah0, Uz[kc], aZ0);                                            \
      aZ1 = MFMA(ah1, Uz[kc], aZ1);                                            \
      aH0 = MFMA(ah0, Un[kc], aH0);                                            \
      aH1 = MFMA(ah1, Un[kc], aH1);                                            \
    }                                                                          \
    _Pragma("unroll") for (int m = 0; m < 2; ++m) {                            \
      f32x4 vR = m ? aR1 : aR0, vZ = m ? aZ1 : aZ0;                            \
      f32x4 vN = m ? aN1 : aN0, vH = m ? aH1 : aH0;                            \
      _Pragma("unroll") for (int r = 0; r < 4; ++r) {                          \
        float rr = sigm(vR[r]);                                                \
        float zz = sigm(vZ[r]);                                                \
        float nn = tanhfast(vN[r] + rr * vH[r]);                               \
        float hN = (1.f - zz) * nn + zz * hreg[m][r];                          \
        if ((T) < degm1[m][r]) hreg[m][r] = hN;                                \
        int row = m * 16 + lq * 4 + r;                                         \
        BW[row][col ^ ((row & 7) << 3)] = f2bf(hreg[m][r]);                    \
      }                                                                        \
    }                                                                          \
    __syncthreads();                                                           \
  } while (0)

#pragma unroll 1
  for (int t = 0; t < tmax; t += 2) {
    GRU_STEP(t, axA, axB, Hb[0], Hb[1]);
    if (t + 1 >= tmax) break;
    GRU_STEP(t + 1, axB, axA, Hb[1], Hb[0]);
  }
#undef GRU_STEP

  // final h -> LDS fp32 for LayerNorm
#pragma unroll
  for (int m = 0; m < 2; ++m)
#pragma unroll
    for (int r = 0; r < 4; ++r) Hf[m * 16 + lq * 4 + r][col] = hreg[m][r];
  __syncthreads();

  // LayerNorm (16 threads/node) + deg==1 override -> Ft (bf16, swizzled)
  {
    int node = tid >> 4, sub = tid & 15;
    float v[8];
    float s = 0.f, s2 = 0.f;
#pragma unroll
    for (int j = 0; j < 8; ++j) {
      v[j] = Hf[node][sub * 8 + j];
      s += v[j];
      s2 += v[j] * v[j];
    }
    s += __shfl_xor(s, 1, 64); s2 += __shfl_xor(s2, 1, 64);
    s += __shfl_xor(s, 2, 64); s2 += __shfl_xor(s2, 2, 64);
    s += __shfl_xor(s, 4, 64); s2 += __shfl_xor(s2, 4, 64);
    s += __shfl_xor(s, 8, 64); s2 += __shfl_xor(s2, 8, 64);
    float mu = s * (1.f / 128.f);
    float var = s2 * (1.f / 128.f) - mu * mu;
    float rstd = rsqrtf(var + 1e-5f);
    bool isd1 = (deg_s[node] == 1);
    const u16* f1 = featb + (size_t)neigh_s[0][node] * DH + sub * 8;
    uint4 fv = *(const uint4*)f1;
    const u16* fp = (const u16*)&fv;
    u16 ob[8];
#pragma unroll
    for (int j = 0; j < 8; ++j) {
      int d = sub * 8 + j;
      float ln = (v[j] - mu) * rstd * gamma[d] + beta[d];
      ob[j] = isd1 ? fp[j] : f2bf(ln);
    }
    int e = (sub * 8) ^ ((node & 7) << 3);
    uint4 pk;
    pk.x = ob[0] | ((u32)ob[1] << 16);
    pk.y = ob[2] | ((u32)ob[3] << 16);
    pk.z = ob[4] | ((u32)ob[5] << 16);
    pk.w = ob[6] | ((u32)ob[7] << 16);
    *(uint4*)&Ft[node][e] = pk;
  }
  __syncthreads();

  // classifier: wave w<7 computes class columns [16w,16w+16)
  if (w < 7) {
    f32x4 c0 = splat4(0.f), c1 = splat4(0.f);
#pragma unroll
    for (int kc = 0; kc < 4; ++kc) {
      int ko = kc * 32 + lq * 8;
      short8 a0 = *(const short8*)&Ft[l16][ko ^ swzA];
      short8 a1 = *(const short8*)&Ft[16 + l16][ko ^ swzA];
      short8 b = *(const short8*)(wcb + (size_t)col * DH + ko);
      c0 = MFMA(a0, b, c0);
      c1 = MFMA(a1, b, c1);
    }
    if (col < NCLS) {
      float bcv = bc[col];
#pragma unroll
      for (int m = 0; m < 2; ++m)
#pragma unroll
        for (int r = 0; r < 4; ++r) {
          float vv = (m ? c1[r] : c0[r]) + bcv;
          int rowg = nid_s[m * 16 + lq * 4 + r];
          out[(size_t)rowg * NCLS + col] = vv;
        }
    }
  }
}

extern "C" void kernel_launch(void* const* d_in, const int* in_sizes, int n_in,
                              void* d_out, int out_size, void* d_ws, size_t ws_size,
                              hipStream_t stream) {
  const int* token = (const int*)d_in[0];
  const int* neigh = (const int*)d_in[1];
  const int* deg = (const int*)d_in[2];
  const float* emb = (const float*)d_in[3];
  const float* wih = (const float*)d_in[4];
  const float* whh = (const float*)d_in[5];
  const float* bih = (const float*)d_in[6];
  const float* bhh = (const float*)d_in[7];
  const float* gamma = (const float*)d_in[8];
  const float* beta = (const float*)d_in[9];
  const float* wc = (const float*)d_in[10];
  const float* bc = (const float*)d_in[11];
  float* out = (float*)d_out;

  u16* featb = (u16*)d_ws;                    // 6,400,000 u16 = 12.8 MB
  u16* wihb = featb + (size_t)NSRC * DH;      // 49152
  u16* whhb = wihb + 384 * DH;                // 49152
  u16* wcb = whhb + 384 * DH;                 // 14336
  int* perm = (int*)(wcb + 112 * DH);         // 32000
  int* blkhist = perm + NDST;                 // 2000
  int* offs = blkhist + SBLK * 16;            // 2000
  int* base16 = offs + SBLK * 16;             // 16

  hipLaunchKernelGGL(k_prep, dim3(192), dim3(256), 0, stream, wih, whh, wc, wihb, whhb, wcb);
  hipLaunchKernelGGL(k_embed, dim3((NSRC * 16 + 255) / 256), dim3(256), 0, stream, token, emb, featb);
  hipLaunchKernelGGL(k_hist, dim3(SBLK), dim3(256), 0, stream, deg, blkhist);
  hipLaunchKernelGGL(k_scan, dim3(1), dim3(64), 0, stream, blkhist, offs, base16);
  hipLaunchKernelGGL(k_scatter, dim3(SBLK), dim3(256), 0, stream, deg, offs, base16, perm);
  hipLaunchKernelGGL(k_gru, dim3(NDST / 32), dim3(512), 0, stream, neigh, deg, perm, featb,
                     wihb, whhb, bih, bhh, gamma, beta, wcb, bc, out);
}

// Round 4
// 218.679 us; speedup vs baseline: 1.6158x; 1.2300x over previous
//
#include <hip/hip_runtime.h>

typedef unsigned short u16;
typedef unsigned int u32;
typedef __attribute__((ext_vector_type(8))) short short8;
typedef __attribute__((ext_vector_type(4))) float f32x4;

#define NDST 32000
#define NSRC 50000
#define MAXDEG 16
#define DH 128
#define NCLS 104
#define SBLK 125   // 32000/256 sort blocks
#define NTILE 1000 // 32000/32 GRU tiles
#define GRID_GRU 256

#define MFMA(a, b, c) __builtin_amdgcn_mfma_f32_16x16x32_bf16(a, b, c, 0, 0, 0)

__device__ __forceinline__ u16 f2bf(float f) {
  union { float f; u32 u; } v; v.f = f;
  return (u16)((v.u + 0x7FFFu + ((v.u >> 16) & 1u)) >> 16);
}
__device__ __forceinline__ float bf2f(u16 x) {
  union { u32 u; float f; } v; v.u = (u32)x << 16;
  return v.f;
}
__device__ __forceinline__ float sigm(float x) { return 1.f / (1.f + __expf(-x)); }
__device__ __forceinline__ float tanhfast(float x) {
  float ax = fabsf(x);
  float e = __expf(2.f * ax);
  float t = 1.f - 2.f / (e + 1.f);
  return copysignf(t, x);
}
__device__ __forceinline__ f32x4 splat4(float x) { f32x4 v = {x, x, x, x}; return v; }

// Convert GRU/classifier weights to bf16; pad classifier weight to 112 rows.
__global__ void k_prep(const float* __restrict__ wih, const float* __restrict__ whh,
                       const float* __restrict__ wc,
                       u16* __restrict__ wihb, u16* __restrict__ whhb, u16* __restrict__ wcb) {
  int i = blockIdx.x * 256 + threadIdx.x;
  if (i < 384 * DH) { wihb[i] = f2bf(wih[i]); whhb[i] = f2bf(whh[i]); }
  if (i < 112 * DH) { int r = i >> 7; wcb[i] = (r < NCLS) ? f2bf(wc[i]) : (u16)0; }
}

// Convert embedding table fp32 -> bf16 (halves gather traffic in k_embed).
__global__ void k_embcvt(const float* __restrict__ emb, u16* __restrict__ embb) {
  int i = blockIdx.x * 256 + threadIdx.x;  // one thread per 8 elems
  const float* p = emb + (size_t)i * 8;
  u16 u[8];
#pragma unroll
  for (int j = 0; j < 8; ++j) u[j] = f2bf(p[j]);
  uint4 pk;
  pk.x = u[0] | ((u32)u[1] << 16);
  pk.y = u[2] | ((u32)u[3] << 16);
  pk.z = u[4] | ((u32)u[5] << 16);
  pk.w = u[6] | ((u32)u[7] << 16);
  *reinterpret_cast<uint4*>(embb + (size_t)i * 8) = pk;
}

// feat_src = mean over 4 subtoken bf16 embeddings -> bf16 [NSRC][128].
__global__ void k_embed(const int* __restrict__ token, const u16* __restrict__ embb,
                        u16* __restrict__ featb) {
  int gid = blockIdx.x * 256 + threadIdx.x;
  if (gid >= NSRC * 16) return;
  int n = gid >> 4, c = gid & 15;  // 16 threads/node, 8 elems each
  const int* tk = token + n * 4;
  int t0 = tk[0], t1 = tk[1], t2 = tk[2], t3 = tk[3];
  short8 e0 = *(const short8*)(embb + (size_t)t0 * DH + c * 8);
  short8 e1 = *(const short8*)(embb + (size_t)t1 * DH + c * 8);
  short8 e2 = *(const short8*)(embb + (size_t)t2 * DH + c * 8);
  short8 e3 = *(const short8*)(embb + (size_t)t3 * DH + c * 8);
  u16 u[8];
#pragma unroll
  for (int j = 0; j < 8; ++j) {
    float a = bf2f((u16)e0[j]) + bf2f((u16)e1[j]) + bf2f((u16)e2[j]) + bf2f((u16)e3[j]);
    u[j] = f2bf(a * 0.25f);
  }
  uint4 pk;
  pk.x = u[0] | ((u32)u[1] << 16);
  pk.y = u[2] | ((u32)u[3] << 16);
  pk.z = u[4] | ((u32)u[5] << 16);
  pk.w = u[6] | ((u32)u[7] << 16);
  *reinterpret_cast<uint4*>(featb + (size_t)n * DH + c * 8) = pk;
}

// ---- degree counting sort ----
__global__ void k_hist(const int* __restrict__ deg, int* __restrict__ blkhist) {
  __shared__ int h[16];
  int tid = threadIdx.x;
  if (tid < 16) h[tid] = 0;
  __syncthreads();
  int node = blockIdx.x * 256 + tid;
  atomicAdd(&h[deg[node] - 1], 1);
  __syncthreads();
  if (tid < 16) blkhist[blockIdx.x * 16 + tid] = h[tid];
}

// parallel scan: 256 threads = 16 classes x 16 lane-groups of 8 blocks each
__global__ void k_scan(const int* __restrict__ blkhist, int* __restrict__ offs,
                       int* __restrict__ base16) {
  __shared__ int tot_s[16];
  int t = threadIdx.x;
  int k = t >> 4, i = t & 15;
  int loc[8];
  int s = 0;
#pragma unroll
  for (int b = 0; b < 8; ++b) {
    int bb = i * 8 + b;
    int v = (bb < SBLK) ? blkhist[bb * 16 + k] : 0;
    loc[b] = s;
    s += v;
  }
  int ps = s;
#pragma unroll
  for (int d = 1; d < 16; d <<= 1) {
    int o = __shfl_up(ps, d, 16);
    if (i >= d) ps += o;
  }
  int excl = ps - s;
#pragma unroll
  for (int b = 0; b < 8; ++b) {
    int bb = i * 8 + b;
    if (bb < SBLK) offs[bb * 16 + k] = excl + loc[b];
  }
  if (i == 15) tot_s[k] = ps;
  __syncthreads();
  if (t == 0) {
    int run = 0;
    for (int q = 0; q < 16; ++q) { base16[q] = run; run += tot_s[q]; }
  }
}

__global__ void k_scatter(const int* __restrict__ deg, const int* __restrict__ offs,
                          const int* __restrict__ base16, int* __restrict__ perm) {
  __shared__ int lc[16];
  int tid = threadIdx.x;
  if (tid < 16) lc[tid] = 0;
  __syncthreads();
  int node = blockIdx.x * 256 + tid;
  int k = deg[node] - 1;
  int p = atomicAdd(&lc[k], 1);
  perm[base16[k] + offs[blockIdx.x * 16 + k] + p] = node;
}

// ---- persistent fused GRU + LN + classifier ----
// 256 blocks x 512 threads (8 waves, 2/SIMD). Each block loads weights ONCE
// into pinned registers (96 VGPR/lane), then processes 4 degree-sorted
// 32-node tiles (serpentine assignment for balance).
__global__ __launch_bounds__(512, 2) void k_gru(
    const int* __restrict__ neigh, const int* __restrict__ deg,
    const int* __restrict__ perm, const u16* __restrict__ featb,
    const u16* __restrict__ wihb, const u16* __restrict__ whhb,
    const float* __restrict__ bih, const float* __restrict__ bhh,
    const float* __restrict__ gamma, const float* __restrict__ beta,
    const u16* __restrict__ wcb, const float* __restrict__ bc,
    float* __restrict__ out) {
  __shared__ u16 Hb[2][32][DH];
  __shared__ int nid_s[32];
  __shared__ int neigh_s[MAXDEG][32];
  __shared__ int deg_s[32];
  __shared__ float Hf[32][DH + 1];
  __shared__ u16 Ft[32][DH];
  __shared__ float gam_s[DH], bet_s[DH];

  const int tid = threadIdx.x;
  const int w = tid >> 6;
  const int l = tid & 63;
  const int l16 = l & 15;
  const int lq = l >> 4;
  const int col = w * 16 + l16;
  const int swzA = (l16 & 7) << 3;

  if (tid < DH) { gam_s[tid] = gamma[tid]; bet_s[tid] = beta[tid]; }

  // ---- weights resident: 24 x short8 = 96 VGPR, pinned via volatile asm ----
  short8 Wr[4], Wz[4], Wn[4], Ur[4], Uz[4], Un[4];
#pragma unroll
  for (int kc = 0; kc < 4; ++kc) {
    int ko = kc * 32 + lq * 8;
    const u16* pw = wihb + (size_t)col * DH + ko;
    const u16* pu = whhb + (size_t)col * DH + ko;
    Wr[kc] = *(const short8*)pw;
    Wz[kc] = *(const short8*)(pw + DH * DH);
    Wn[kc] = *(const short8*)(pw + 2 * DH * DH);
    Ur[kc] = *(const short8*)pu;
    Uz[kc] = *(const short8*)(pu + DH * DH);
    Un[kc] = *(const short8*)(pu + 2 * DH * DH);
  }
  float bR = bih[col] + bhh[col];
  float bZ = bih[DH + col] + bhh[DH + col];
  float bXN = bih[2 * DH + col];
  float bHN = bhh[2 * DH + col];
  asm volatile("" : "+v"(Wr[0]), "+v"(Wr[1]), "+v"(Wr[2]), "+v"(Wr[3]));
  asm volatile("" : "+v"(Wz[0]), "+v"(Wz[1]), "+v"(Wz[2]), "+v"(Wz[3]));
  asm volatile("" : "+v"(Wn[0]), "+v"(Wn[1]), "+v"(Wn[2]), "+v"(Wn[3]));
  asm volatile("" : "+v"(Ur[0]), "+v"(Ur[1]), "+v"(Ur[2]), "+v"(Ur[3]));
  asm volatile("" : "+v"(Uz[0]), "+v"(Uz[1]), "+v"(Uz[2]), "+v"(Uz[3]));
  asm volatile("" : "+v"(Un[0]), "+v"(Un[1]), "+v"(Un[2]), "+v"(Un[3]));
  asm volatile("" : "+v"(bR), "+v"(bZ), "+v"(bXN), "+v"(bHN));

#pragma unroll 1
  for (int g = 0; g < 4; ++g) {
    int tile = (g & 1) ? ((g + 1) * GRID_GRU - 1 - (int)blockIdx.x)
                       : (g * GRID_GRU + (int)blockIdx.x);
    if (tile >= NTILE) continue;  // blockIdx-uniform -> no barrier divergence

    __syncthreads();  // previous tile's LDS consumers done
    if (tid < 32) nid_s[tid] = perm[tile * 32 + tid];
    __syncthreads();
    {
      int node = tid >> 4, t = tid & 15;
      neigh_s[t][node] = neigh[(size_t)nid_s[node] * MAXDEG + t];
    }
    if (tid < 32) deg_s[tid] = deg[nid_s[tid]];
    {
      uint4 z = {0, 0, 0, 0};
      ((uint4*)Hb[0])[tid] = z;  // 32*128*2B / 16B == 512
    }
    __syncthreads();

    const int tmax = deg_s[31] - 1;  // sorted ascending -> slot 31 is max
    int degm1[2][4];
#pragma unroll
    for (int m = 0; m < 2; ++m)
#pragma unroll
      for (int r = 0; r < 4; ++r) degm1[m][r] = deg_s[m * 16 + lq * 4 + r] - 1;
    float hreg[2][4] = {{0, 0, 0, 0}, {0, 0, 0, 0}};

    if (tmax > 0) {
      short8 axA[2][4], axB[2][4];
      {
        int s0 = neigh_s[0][l16], s1 = neigh_s[0][16 + l16];
#pragma unroll
        for (int kc = 0; kc < 4; ++kc) {
          int ko = kc * 32 + lq * 8;
          axA[0][kc] = *(const short8*)(featb + (size_t)s0 * DH + ko);
          axA[1][kc] = *(const short8*)(featb + (size_t)s1 * DH + ko);
        }
      }

#define GRU_STEP(T, AXC, AXN, BR, BW)                                          \
  do {                                                                         \
    int sn0 = neigh_s[(T) + 1][l16], sn1 = neigh_s[(T) + 1][16 + l16];         \
    _Pragma("unroll") for (int kc = 0; kc < 4; ++kc) {                         \
      int ko = kc * 32 + lq * 8;                                               \
      AXN[0][kc] = *(const short8*)(featb + (size_t)sn0 * DH + ko);            \
      AXN[1][kc] = *(const short8*)(featb + (size_t)sn1 * DH + ko);            \
    }                                                                          \
    f32x4 aR0 = splat4(bR), aR1 = splat4(bR), aZ0 = splat4(bZ),                \
          aZ1 = splat4(bZ), aN0 = splat4(bXN), aN1 = splat4(bXN),              \
          aH0 = splat4(bHN), aH1 = splat4(bHN);                                \
    _Pragma("unroll") for (int kc = 0; kc < 4; ++kc) {                         \
      int ko = kc * 32 + lq * 8;                                               \
      short8 ah0 = *(const short8*)&BR[l16][ko ^ swzA];                        \
      short8 ah1 = *(const short8*)&BR[16 + l16][ko ^ swzA];                   \
      aR0 = MFMA(AXC[0][kc], Wr[kc], aR0);                                     \
      aR1 = MFMA(AXC[1][kc], Wr[kc], aR1);                                     \
      aZ0 = MFMA(AXC[0][kc], Wz[kc], aZ0);                                     \
      aZ1 = MFMA(AXC[1][kc], Wz[kc], aZ1);                                     \
      aN0 = MFMA(AXC[0][kc], Wn[kc], aN0);                                     \
      aN1 = MFMA(AXC[1][kc], Wn[kc], aN1);                                     \
      aR0 = MFMA(ah0, Ur[kc], aR0);                                            \
      aR1 = MFMA(ah1, Ur[kc], aR1);                                            \
      aZ0 = MFMA(ah0, Uz[kc], aZ0);                                            \
      aZ1 = MFMA(ah1, Uz[kc], aZ1);                                            \
      aH0 = MFMA(ah0, Un[kc], aH0);                                            \
      aH1 = MFMA(ah1, Un[kc], aH1);                                            \
    }                                                                          \
    _Pragma("unroll") for (int m = 0; m < 2; ++m) {                            \
      f32x4 vR = m ? aR1 : aR0, vZ = m ? aZ1 : aZ0;                            \
      f32x4 vN = m ? aN1 : aN0, vH = m ? aH1 : aH0;                            \
      _Pragma("unroll") for (int r = 0; r < 4; ++r) {                          \
        float rr = sigm(vR[r]);                                                \
        float zz = sigm(vZ[r]);                                                \
        float nn = tanhfast(vN[r] + rr * vH[r]);                               \
        float hN = (1.f - zz) * nn + zz * hreg[m][r];                          \
        if ((T) < degm1[m][r]) hreg[m][r] = hN;                                \
        int row = m * 16 + lq * 4 + r;                                         \
        BW[row][col ^ ((row & 7) << 3)] = f2bf(hreg[m][r]);                    \
      }                                                                        \
    }                                                                          \
    __syncthreads();                                                           \
  } while (0)

#pragma unroll 1
      for (int t = 0; t < tmax; t += 2) {
        GRU_STEP(t, axA, axB, Hb[0], Hb[1]);
        if (t + 1 >= tmax) break;
        GRU_STEP(t + 1, axB, axA, Hb[1], Hb[0]);
      }
#undef GRU_STEP
    }

    // final h -> LDS fp32 for LayerNorm
#pragma unroll
    for (int m = 0; m < 2; ++m)
#pragma unroll
      for (int r = 0; r < 4; ++r) Hf[m * 16 + lq * 4 + r][col] = hreg[m][r];
    __syncthreads();

    // LayerNorm (16 threads/node) + deg==1 override -> Ft (bf16, swizzled)
    {
      int node = tid >> 4, sub = tid & 15;
      float v[8];
      float s = 0.f, s2 = 0.f;
#pragma unroll
      for (int j = 0; j < 8; ++j) {
        v[j] = Hf[node][sub * 8 + j];
        s += v[j];
        s2 += v[j] * v[j];
      }
      s += __shfl_xor(s, 1, 64); s2 += __shfl_xor(s2, 1, 64);
      s += __shfl_xor(s, 2, 64); s2 += __shfl_xor(s2, 2, 64);
      s += __shfl_xor(s, 4, 64); s2 += __shfl_xor(s2, 4, 64);
      s += __shfl_xor(s, 8, 64); s2 += __shfl_xor(s2, 8, 64);
      float mu = s * (1.f / 128.f);
      float var = s2 * (1.f / 128.f) - mu * mu;
      float rstd = rsqrtf(var + 1e-5f);
      bool isd1 = (deg_s[node] == 1);
      uint4 fv = *(const uint4*)(featb + (size_t)neigh_s[0][node] * DH + sub * 8);
      const u16* fp = (const u16*)&fv;
      u16 ob[8];
#pragma unroll
      for (int j = 0; j < 8; ++j) {
        int d = sub * 8 + j;
        float ln = (v[j] - mu) * rstd * gam_s[d] + bet_s[d];
        ob[j] = isd1 ? fp[j] : f2bf(ln);
      }
      int e = (sub * 8) ^ ((node & 7) << 3);
      uint4 pk;
      pk.x = ob[0] | ((u32)ob[1] << 16);
      pk.y = ob[2] | ((u32)ob[3] << 16);
      pk.z = ob[4] | ((u32)ob[5] << 16);
      pk.w = ob[6] | ((u32)ob[7] << 16);
      *(uint4*)&Ft[node][e] = pk;
    }
    __syncthreads();

    // classifier: wave w<7 computes class columns [16w,16w+16)
    if (w < 7) {
      f32x4 c0 = splat4(0.f), c1 = splat4(0.f);
#pragma unroll
      for (int kc = 0; kc < 4; ++kc) {
        int ko = kc * 32 + lq * 8;
        short8 a0 = *(const short8*)&Ft[l16][ko ^ swzA];
        short8 a1 = *(const short8*)&Ft[16 + l16][ko ^ swzA];
        short8 b = *(const short8*)(wcb + (size_t)col * DH + ko);
        c0 = MFMA(a0, b, c0);
        c1 = MFMA(a1, b, c1);
      }
      if (col < NCLS) {
        float bcv = bc[col];
#pragma unroll
        for (int m = 0; m < 2; ++m)
#pragma unroll
          for (int r = 0; r < 4; ++r) {
            float vv = (m ? c1[r] : c0[r]) + bcv;
            int rowg = nid_s[m * 16 + lq * 4 + r];
            out[(size_t)rowg * NCLS + col] = vv;
          }
      }
    }
  }
}

extern "C" void kernel_launch(void* const* d_in, const int* in_sizes, int n_in,
                              void* d_out, int out_size, void* d_ws, size_t ws_size,
                              hipStream_t stream) {
  const int* token = (const int*)d_in[0];
  const int* neigh = (const int*)d_in[1];
  const int* deg = (const int*)d_in[2];
  const float* emb = (const float*)d_in[3];
  const float* wih = (const float*)d_in[4];
  const float* whh = (const float*)d_in[5];
  const float* bih = (const float*)d_in[6];
  const float* bhh = (const float*)d_in[7];
  const float* gamma = (const float*)d_in[8];
  const float* beta = (const float*)d_in[9];
  const float* wc = (const float*)d_in[10];
  const float* bc = (const float*)d_in[11];
  float* out = (float*)d_out;

  u16* featb = (u16*)d_ws;                    // 6,400,000 u16 = 12.8 MB
  u16* wihb = featb + (size_t)NSRC * DH;      // 49152
  u16* whhb = wihb + 384 * DH;                // 49152
  u16* wcb = whhb + 384 * DH;                 // 14336
  u16* embb = wcb + 112 * DH;                 // 32000*128 = 4,096,000 u16 = 8.2 MB
  int* perm = (int*)(embb + (size_t)32000 * DH);
  int* blkhist = perm + NDST;
  int* offs = blkhist + SBLK * 16;
  int* base16 = offs + SBLK * 16;

  hipLaunchKernelGGL(k_prep, dim3(192), dim3(256), 0, stream, wih, whh, wc, wihb, whhb, wcb);
  hipLaunchKernelGGL(k_embcvt, dim3(2000), dim3(256), 0, stream, emb, embb);
  hipLaunchKernelGGL(k_embed, dim3((NSRC * 16 + 255) / 256), dim3(256), 0, stream, token, embb, featb);
  hipLaunchKernelGGL(k_hist, dim3(SBLK), dim3(256), 0, stream, deg, blkhist);
  hipLaunchKernelGGL(k_scan, dim3(1), dim3(256), 0, stream, blkhist, offs, base16);
  hipLaunchKernelGGL(k_scatter, dim3(SBLK), dim3(256), 0, stream, deg, offs, base16, perm);
  hipLaunchKernelGGL(k_gru, dim3(GRID_GRU), dim3(512), 0, stream, neigh, deg, perm, featb,
                     wihb, whhb, bih, bhh, gamma, beta, wcb, bc, out);
}